// Round 6
// baseline (790.819 us; speedup 1.0000x reference)
//
#include <hip/hip_runtime.h>
#include <math.h>

#define Tc 2048
#define Dc 1024
#define Hc 16
#define HDc 64
#define BT 4096                     // B*T
#define SCALE 0.35355339059327379f  // 64^-0.25

typedef _Float16 f16;
typedef __attribute__((ext_vector_type(4))) _Float16 f16x4;
typedef __attribute__((ext_vector_type(8))) _Float16 f16x8;
typedef __attribute__((ext_vector_type(4))) float f32x4;

__device__ __forceinline__ void gload16(const f16* g, f16* l)
{
    __builtin_amdgcn_global_load_lds(
        (const __attribute__((address_space(1))) void*)g,
        (__attribute__((address_space(3))) void*)l, 16, 0, 0);
}

// 16-lane allreduce via DPP (VALU pipe, no LDS)
template <int C>
__device__ __forceinline__ float fdpp(float x)
{
    return __int_as_float(__builtin_amdgcn_update_dpp(
        0, __float_as_int(x), C, 0xF, 0xF, true));
}
__device__ __forceinline__ float rmax16(float v)
{
    v = fmaxf(v, fdpp<0xB1>(v));    // quad_perm xor1
    v = fmaxf(v, fdpp<0x4E>(v));    // quad_perm xor2
    v = fmaxf(v, fdpp<0x124>(v));   // row_ror:4
    v = fmaxf(v, fdpp<0x128>(v));   // row_ror:8
    return v;
}
__device__ __forceinline__ float rsum16(float v)
{
    v += fdpp<0xB1>(v);
    v += fdpp<0x4E>(v);
    v += fdpp<0x124>(v);
    v += fdpp<0x128>(v);
    return v;
}

// ---------------------------------------------------------------------------
// fused casts: 8 units of 1M floats (x in 4 chunks + 4 weights)
// ---------------------------------------------------------------------------
__global__ __launch_bounds__(256)
void cast_kernel(const float* __restrict__ x,
                 const float* __restrict__ Wq, const float* __restrict__ Wk,
                 const float* __restrict__ Wv, const float* __restrict__ Wo,
                 f16* __restrict__ xh,
                 f16* __restrict__ Wqh, f16* __restrict__ Wkh,
                 f16* __restrict__ Wvh, f16* __restrict__ Woh)
{
    const int u = blockIdx.y;
    const float* s; f16* d;
    if (u < 4) { s = x + (size_t)u * (1u << 20); d = xh + (size_t)u * (1u << 20); }
    else switch (u) {
        case 4:  s = Wq; d = Wqh; break;
        case 5:  s = Wk; d = Wkh; break;
        case 6:  s = Wv; d = Wvh; break;
        default: s = Wo; d = Woh; break;
    }
    int i = blockIdx.x * 256 + threadIdx.x;
    float4 v = ((const float4*)s)[i];
    f16x4 o = {(f16)v.x, (f16)v.y, (f16)v.z, (f16)v.w};
    ((f16x4*)d)[i] = o;
}

// ---------------------------------------------------------------------------
// 2-phase double-buffered GEMM core (r5, frozen): 128x64 tile, BK=64.
// ---------------------------------------------------------------------------
#define GEMM_BODY(Aptr, Bptr)                                                        \
    __shared__ f16 As[2][128 * 64];                                                  \
    __shared__ f16 Bs[2][64 * 64];                                                   \
    const int tid = threadIdx.x;                                                     \
    const int w = tid >> 6, l = tid & 63;                                            \
    const int lr = l & 15, lq = l >> 4;                                              \
    const int m0 = blockIdx.y * 128, n0 = blockIdx.x * 64;                           \
    const int srow8 = l >> 3, sslot = l & 7;                                         \
    f32x4 acc[2][4] = {};                                                            \
    auto STAGE = [&](int b, int k0) {                                                \
        _Pragma("unroll")                                                            \
        for (int c = 0; c < 6; c++) {                                                \
            int chunk = w * 6 + c;                                                   \
            if (chunk < 16) {                                                        \
                int row = chunk * 8 + srow8;                                         \
                int col = (sslot ^ (row & 7)) * 8;                                   \
                gload16(&Aptr[(size_t)(m0 + row) * Dc + k0 + col],                   \
                        &As[b][chunk * 512]);                                        \
            } else {                                                                 \
                int row = (chunk - 16) * 8 + srow8;                                  \
                int col = (sslot ^ (row & 7)) * 8;                                   \
                gload16(&Bptr[(size_t)(n0 + row) * Dc + k0 + col],                   \
                        &Bs[b][(chunk - 16) * 512]);                                 \
            }                                                                        \
        }                                                                            \
    };                                                                               \
    STAGE(0, 0);                                                                     \
    __syncthreads();                                                                 \
    int cur = 0;                                                                     \
    for (int k0 = 0; k0 < Dc; k0 += 64) {                                            \
        if (k0 + 64 < Dc) STAGE(cur ^ 1, k0 + 64);                                   \
        _Pragma("unroll")                                                            \
        for (int kk = 0; kk < 2; kk++) {                                             \
            f16x8 af[2], bf[4];                                                      \
            _Pragma("unroll")                                                        \
            for (int mi = 0; mi < 2; mi++) {                                         \
                int row = 32 * w + 16 * mi + lr;                                     \
                int bo = (lq * 16 + kk * 64) ^ ((row & 7) << 4);                     \
                af[mi] = *(const f16x8*)((const char*)&As[cur][0] + row * 128 + bo); \
            }                                                                        \
            _Pragma("unroll")                                                        \
            for (int ni = 0; ni < 4; ni++) {                                         \
                int row = 16 * ni + lr;                                              \
                int bo = (lq * 16 + kk * 64) ^ ((row & 7) << 4);                     \
                bf[ni] = *(const f16x8*)((const char*)&Bs[cur][0] + row * 128 + bo); \
            }                                                                        \
            _Pragma("unroll")                                                        \
            for (int mi = 0; mi < 2; mi++)                                           \
                _Pragma("unroll")                                                    \
                for (int ni = 0; ni < 4; ni++)                                       \
                    acc[mi][ni] = __builtin_amdgcn_mfma_f32_16x16x32_f16(            \
                        af[mi], bf[ni], acc[mi][ni], 0, 0, 0);                       \
        }                                                                            \
        __syncthreads();                                                             \
        cur ^= 1;                                                                    \
    }

// fused QKV projection + RoPE/scale epilogue, store f16 (B,H,T,HD)
__global__ __launch_bounds__(256, 3)
void qkv_proj_kernel(const f16* __restrict__ xh,
                     const f16* __restrict__ Wqh, const f16* __restrict__ Wkh,
                     const f16* __restrict__ Wvh,
                     const float* __restrict__ bq, const float* __restrict__ bv,
                     f16* __restrict__ qh, f16* __restrict__ kh, f16* __restrict__ vh,
                     const float* __restrict__ cosp, const float* __restrict__ sinp)
{
    const int mode = blockIdx.z;
    const f16* W = (mode == 0) ? Wqh : (mode == 1 ? Wkh : Wvh);
    const float* bias = (mode == 0) ? bq : (mode == 2 ? bv : nullptr);
    f16* dst = (mode == 0) ? qh : (mode == 1 ? kh : vh);

    GEMM_BODY(xh, W)

    #pragma unroll
    for (int mi = 0; mi < 2; mi++) {
        #pragma unroll
        for (int ni = 0; ni < 4; ni++) {
            #pragma unroll
            for (int i = 0; i < 4; i++) {
                int gm = m0 + 32 * w + 16 * mi + lq * 4 + i;
                int gn = n0 + 16 * ni + lr;
                float v = acc[mi][ni][i];
                if (bias) v += bias[gn];
                int b = gm >> 11, t = gm & 2047;
                int h = gn >> 6, d = gn & 63;
                if (mode != 2) {
                    float pv = __shfl_xor(v, 1, 64);   // partner col gn^1
                    int p = d >> 1;
                    float c = cosp[t * 32 + p], s = sinp[t * 32 + p];
                    v = (d & 1) ? (pv * s + v * c) : (v * c - pv * s);
                    v *= SCALE;
                }
                dst[((size_t)(b * Hc + h) * Tc + t) * HDc + d] = (f16)v;
            }
        }
    }
}

// out projection: out(BT x Dc) = wvh * Wo^T + bo, fp32 store
__global__ __launch_bounds__(256, 3)
void out_proj_kernel(const f16* __restrict__ A, const f16* __restrict__ W,
                     const float* __restrict__ bias, float* __restrict__ out)
{
    GEMM_BODY(A, W)

    #pragma unroll
    for (int mi = 0; mi < 2; mi++)
        #pragma unroll
        for (int ni = 0; ni < 4; ni++)
            #pragma unroll
            for (int i = 0; i < 4; i++) {
                int gm = m0 + 32 * w + 16 * mi + lq * 4 + i;
                int gn = n0 + 16 * ni + lr;
                out[(size_t)gm * Dc + gn] = acc[mi][ni][i] + bias[gn];
            }
}

// ---------------------------------------------------------------------------
// score_kernel: qk[z][t][s] = q.k^T (+causal -1e9) for one 128x128 (t,s) tile.
// Computed TRANSPOSED: mfma(A=K, B=Q) so C rows = s, cols = t; with the
// C-layout (col=lane&15, row=lq*4+i) each lane's 4 regs are 4 consecutive
// s-addresses -> natural f32x4 stores (qk row stride is in t).
// Strictly-upper blocks (s0 > t0) take a pure -1e9 fill fast path.
// ---------------------------------------------------------------------------
__global__ __launch_bounds__(256, 4)
void score_kernel(const f16* __restrict__ qh, const f16* __restrict__ kh,
                  float* __restrict__ qk)
{
    const int z = blockIdx.z;
    const int s0 = blockIdx.x * 128;
    const int t0 = blockIdx.y * 128;
    const int tid = threadIdx.x;
    float* C = qk + (size_t)z * Tc * Tc;

    if (s0 > t0) {   // strictly upper: fill -1e9 (128 rows x 128 cols)
        int r = t0 + (tid >> 1);
        float* rowp = C + (size_t)r * Tc + s0 + (tid & 1) * 64;
        f32x4 mv = {-1e9f, -1e9f, -1e9f, -1e9f};
        #pragma unroll
        for (int j = 0; j < 16; j++)
            ((f32x4*)rowp)[j] = mv;
        return;
    }

    __shared__ f16 KT[128 * 64];   // A-tile: K rows s0..s0+127
    __shared__ f16 QT[128 * 64];   // B-tile: Q rows t0..t0+127

    const int w = tid >> 6, l = tid & 63;
    const int lr = l & 15, lq = l >> 4;
    const int srow8 = l >> 3, sslot = l & 7;

    const f16* Qg = qh + (size_t)z * Tc * HDc;
    const f16* Kg = kh + (size_t)z * Tc * HDc;

    // stage both tiles: 32 chunks of 1KB, gload16, GEMM swizzle
    #pragma unroll
    for (int c = 0; c < 8; c++) {
        int chunk = w * 8 + c;
        int row = (chunk & 15) * 8 + srow8;
        int col = (sslot ^ (row & 7)) * 8;
        if (chunk < 16)
            gload16(&Kg[(size_t)(s0 + row) * HDc + col], &KT[chunk * 512]);
        else
            gload16(&Qg[(size_t)(t0 + row) * HDc + col], &QT[(chunk - 16) * 512]);
    }
    __syncthreads();

    // wave w: s-strip rows 32w..32w+31, all 128 t-cols
    f32x4 acc[2][8] = {};
    #pragma unroll
    for (int kk = 0; kk < 2; kk++) {
        f16x8 af[2], bf[8];
        #pragma unroll
        for (int mi = 0; mi < 2; mi++) {
            int row = 32 * w + 16 * mi + lr;
            int bo = (lq * 16 + kk * 64) ^ ((row & 7) << 4);
            af[mi] = *(const f16x8*)((const char*)&KT[0] + row * 128 + bo);
        }
        #pragma unroll
        for (int ni = 0; ni < 8; ni++) {
            int row = 16 * ni + lr;
            int bo = (lq * 16 + kk * 64) ^ ((row & 7) << 4);
            bf[ni] = *(const f16x8*)((const char*)&QT[0] + row * 128 + bo);
        }
        #pragma unroll
        for (int mi = 0; mi < 2; mi++)
            #pragma unroll
            for (int ni = 0; ni < 8; ni++)
                acc[mi][ni] = __builtin_amdgcn_mfma_f32_16x16x32_f16(
                    af[mi], bf[ni], acc[mi][ni], 0, 0, 0);
    }

    // mask + store: lane's 4 regs = s consecutive; row = t
    #pragma unroll
    for (int mi = 0; mi < 2; mi++) {
        int sbase = s0 + 32 * w + 16 * mi + lq * 4;
        #pragma unroll
        for (int ni = 0; ni < 8; ni++) {
            int tg = t0 + 16 * ni + lr;
            f32x4 ov = acc[mi][ni];
            #pragma unroll
            for (int i = 0; i < 4; i++)
                if (sbase + i > tg) ov[i] = -1e9f;
            *(f32x4*)(C + (size_t)tg * Tc + sbase) = ov;
        }
    }
}

// ---------------------------------------------------------------------------
// flash attention (no S writeback — score_kernel owns qk).  r5 structure:
// 25KB-class LDS, launch_bounds(256,6), gload_lds K staging w/ XOR swizzle,
// V transposed via regs, Q hoisted to regs, DPP softmax, setprio on MFMA.
// ---------------------------------------------------------------------------
__global__ __launch_bounds__(256, 6)
void flash_kernel(const f16* __restrict__ qh, const f16* __restrict__ kh,
                  const f16* __restrict__ vh, f16* __restrict__ wvh)
{
    const int z = blockIdx.y;
    const int t0 = (gridDim.x - 1 - blockIdx.x) * 64;   // longest flash loops first
    const int tid = threadIdx.x;
    const int w = tid >> 6, l = tid & 63;
    const int lr = l & 15, lq = l >> 4;

    __shared__ f16 Ks[64][64];    // linear, contents XOR-swizzled (as GEMM tiles)
    __shared__ f16 VsT[64][68];   // [d][s]
    __shared__ f16 Ps[64][68];    // [m][s]

    const f16* Qg = qh + (size_t)z * Tc * HDc;
    const f16* Kg = kh + (size_t)z * Tc * HDc;
    const f16* Vg = vh + (size_t)z * Tc * HDc;

    // Q-hoist: this wave's A-fragments, straight from global (one-time)
    f16x8 aq[2];
    #pragma unroll
    for (int ks = 0; ks < 2; ks++)
        aq[ks] = *(const f16x8*)&Qg[(size_t)(t0 + 16 * w + lr) * HDc + lq * 8 + 32 * ks];

    f32x4 O[4] = {};
    float mrow[4], lrow[4];
    #pragma unroll
    for (int i = 0; i < 4; i++) { mrow[i] = -1e30f; lrow[i] = 0.f; }

    const int srow8 = l >> 3, sslot = l & 7;

    for (int s0 = 0; s0 <= t0; s0 += 64) {
        __syncthreads();   // prior-iteration LDS reads done

        // stage K: gload_lds(16B), linear LDS dest, pre-swizzled global source
        #pragma unroll
        for (int c = 0; c < 2; c++) {
            int chunk = w * 2 + c;
            int row = chunk * 8 + srow8;
            int col = (sslot ^ (row & 7)) * 8;
            gload16(&Kg[(size_t)(s0 + row) * HDc + col],
                    (f16*)((char*)&Ks[0][0] + chunk * 1024));
        }
        // stage V transposed via registers
        {
            const f16* vp = &Vg[(size_t)(s0 + l) * HDc + w * 16];
            f16x8 v0 = *(const f16x8*)vp;
            f16x8 v1 = *(const f16x8*)(vp + 8);
            #pragma unroll
            for (int j = 0; j < 8; j++) {
                VsT[w * 16 + j][l]     = v0[j];
                VsT[w * 16 + 8 + j][l] = v1[j];
            }
        }
        __syncthreads();   // drains vmcnt (gload_lds) + lgkm (ds_writes)

        // S = Q K^T  (wave strip: q-rows 16w..16w+15, all 64 s)
        f32x4 S[4] = {};
        __builtin_amdgcn_s_setprio(1);
        #pragma unroll
        for (int ks = 0; ks < 2; ks++) {
            #pragma unroll
            for (int ni = 0; ni < 4; ni++) {
                int krow = 16 * ni + lr;
                int bo = (lq * 16 + ks * 64) ^ ((krow & 7) << 4);
                f16x8 bk = *(const f16x8*)((const char*)&Ks[0][0] + krow * 128 + bo);
                S[ni] = __builtin_amdgcn_mfma_f32_16x16x32_f16(aq[ks], bk, S[ni], 0, 0, 0);
            }
        }
        __builtin_amdgcn_s_setprio(0);

        if (s0 == t0) {   // diagonal tile: causal mask
            #pragma unroll
            for (int ni = 0; ni < 4; ni++)
                #pragma unroll
                for (int i = 0; i < 4; i++) {
                    int tg = t0 + 16 * w + lq * 4 + i;
                    int sg = s0 + 16 * ni + lr;
                    if (sg > tg) S[ni][i] = -1e9f;
                }
        }

        // online softmax per row (rows live across 16 lanes of a quad)
        #pragma unroll
        for (int i = 0; i < 4; i++) {
            float v = fmaxf(fmaxf(S[0][i], S[1][i]), fmaxf(S[2][i], S[3][i]));
            v = rmax16(v);
            float mnew = fmaxf(mrow[i], v);
            float alpha = __expf(mrow[i] - mnew);
            mrow[i] = mnew;
            float rs = 0.f;
            #pragma unroll
            for (int ni = 0; ni < 4; ni++) {
                float p = __expf(S[ni][i] - mnew);
                S[ni][i] = p;
                rs += p;
            }
            rs = rsum16(rs);
            lrow[i] = lrow[i] * alpha + rs;
            #pragma unroll
            for (int ni = 0; ni < 4; ni++) O[ni][i] *= alpha;
        }

        // P -> LDS (wave-private strip; no cross-wave hazard)
        #pragma unroll
        for (int ni = 0; ni < 4; ni++)
            #pragma unroll
            for (int i = 0; i < 4; i++)
                Ps[16 * w + lq * 4 + i][16 * ni + lr] = (f16)S[ni][i];

        // O += P V
        __builtin_amdgcn_s_setprio(1);
        #pragma unroll
        for (int ks = 0; ks < 2; ks++) {
            f16x8 ap = *(const f16x8*)&Ps[16 * w + lr][lq * 8 + 32 * ks];
            #pragma unroll
            for (int ni = 0; ni < 4; ni++) {
                f16x8 bv = *(const f16x8*)&VsT[16 * ni + lr][lq * 8 + 32 * ks];
                O[ni] = __builtin_amdgcn_mfma_f32_16x16x32_f16(ap, bv, O[ni], 0, 0, 0);
            }
        }
        __builtin_amdgcn_s_setprio(0);
    }

    const int b = z >> 4, h = z & 15;
    #pragma unroll
    for (int ni = 0; ni < 4; ni++)
        #pragma unroll
        for (int i = 0; i < 4; i++) {
            int tg = t0 + 16 * w + lq * 4 + i;
            int d = 16 * ni + lr;
            float o = O[ni][i] / lrow[i];
            wvh[((size_t)(b * Tc + tg)) * Dc + h * HDc + d] = (f16)o;
        }
}

// ---------------------------------------------------------------------------
extern "C" void kernel_launch(void* const* d_in, const int* in_sizes, int n_in,
                              void* d_out, int out_size, void* d_ws, size_t ws_size,
                              hipStream_t stream)
{
    const float* x    = (const float*)d_in[0];
    const float* cosp = (const float*)d_in[2];
    const float* sinp = (const float*)d_in[3];
    const float* Wq   = (const float*)d_in[4];
    const float* bq   = (const float*)d_in[5];
    const float* Wk   = (const float*)d_in[6];
    const float* Wv   = (const float*)d_in[7];
    const float* bv   = (const float*)d_in[8];
    const float* Wo   = (const float*)d_in[9];
    const float* bo   = (const float*)d_in[10];

    float* out = (float*)d_out;
    float* qk  = out + (size_t)BT * Dc;

    f16* ws  = (f16*)d_ws;
    f16* xh  = ws;
    f16* Wqh = xh  + (size_t)BT * Dc;
    f16* Wkh = Wqh + (size_t)Dc * Dc;
    f16* Wvh = Wkh + (size_t)Dc * Dc;
    f16* Woh = Wvh + (size_t)Dc * Dc;
    f16* qh  = Woh + (size_t)Dc * Dc;
    f16* kh  = qh  + (size_t)BT * Dc;
    f16* vh  = kh  + (size_t)BT * Dc;
    f16* wvh = vh  + (size_t)BT * Dc;

    dim3 blk(256);

    cast_kernel<<<dim3(1024, 8), blk, 0, stream>>>(
        x, Wq, Wk, Wv, Wo, xh, Wqh, Wkh, Wvh, Woh);

    qkv_proj_kernel<<<dim3(Dc / 64, BT / 128, 3), blk, 0, stream>>>(
        xh, Wqh, Wkh, Wvh, bq, bv, qh, kh, vh, cosp, sinp);

    flash_kernel<<<dim3(Tc / 64, 32), blk, 0, stream>>>(qh, kh, vh, wvh);

    out_proj_kernel<<<dim3(Dc / 64, BT / 128), blk, 0, stream>>>(wvh, Woh, bo, out);

    score_kernel<<<dim3(Tc / 128, Tc / 128, 32), blk, 0, stream>>>(qh, kh, qk);
}